// Round 1
// baseline (1060.455 us; speedup 1.0000x reference)
//
#include <hip/hip_runtime.h>

#define TT 1024      // tokens
#define HH 2048      // hidden
#define EE 16        // experts
#define TK 4         // top-k
#define II 1408      // expert intermediate
#define ISS 2816     // shared intermediate (I * 2 shared experts)

typedef __bf16 bf16_t;
typedef __bf16 bf16x8 __attribute__((ext_vector_type(8)));
typedef __bf16 bf16x4 __attribute__((ext_vector_type(4)));
typedef float  f32x4  __attribute__((ext_vector_type(4)));

constexpr int BM = 64, BN = 64, BK = 64;
constexpr int LPAD = 8;   // +8 bf16 = +16B row pad -> bank step 4, conflict-free

#define MFMA16(a, b, c) __builtin_amdgcn_mfma_f32_16x16x32_bf16((a), (b), (c), 0, 0, 0)

// ---------------- small kernels ----------------

__global__ __launch_bounds__(256) void convert_x_kernel(
    const float4* __restrict__ x4, bf16_t* __restrict__ xb, int n4,
    int* __restrict__ counts, int* __restrict__ fills)
{
    int i = blockIdx.x * 256 + threadIdx.x;
    if (i < n4) {
        float4 v = x4[i];
        bf16x4 o;
        o[0] = (bf16_t)v.x; o[1] = (bf16_t)v.y; o[2] = (bf16_t)v.z; o[3] = (bf16_t)v.w;
        *(bf16x4*)(xb + (size_t)i * 4) = o;
    }
    if (blockIdx.x == 0 && threadIdx.x < EE) {
        counts[threadIdx.x] = 0;
        fills[threadIdx.x]  = 0;
    }
}

// one wave per token; fp32 logits (selection accuracy), p=exp(l-max), top4, renorm
__global__ __launch_bounds__(64) void router_kernel(
    const float* __restrict__ x, const float* __restrict__ Wg,
    int* __restrict__ topk_ids, float* __restrict__ topk_w, int* __restrict__ counts)
{
    const int t = blockIdx.x;
    const int lane = threadIdx.x;
    float acc[EE];
#pragma unroll
    for (int e = 0; e < EE; ++e) acc[e] = 0.0f;
    const float* xrow = x + (size_t)t * HH;
    for (int k = lane; k < HH; k += 64) {
        float xv = xrow[k];
        const float* wr = Wg + (size_t)k * EE;
#pragma unroll
        for (int e = 0; e < EE; ++e) acc[e] = fmaf(xv, wr[e], acc[e]);
    }
#pragma unroll
    for (int e = 0; e < EE; ++e) {
        float v = acc[e];
        for (int off = 32; off; off >>= 1) v += __shfl_xor(v, off, 64);
        acc[e] = v;
    }
    if (lane == 0) {
        float m = acc[0];
#pragma unroll
        for (int e = 1; e < EE; ++e) m = fmaxf(m, acc[e]);
        float p[EE];
#pragma unroll
        for (int e = 0; e < EE; ++e) p[e] = expf(acc[e] - m);
        unsigned sel = 0;
        int ids[TK]; float w[TK]; float s = 0.0f;
        for (int j = 0; j < TK; ++j) {
            float best = -1.0f; int bi = 0;
            for (int e = 0; e < EE; ++e) {
                if (!((sel >> e) & 1u) && p[e] > best) { best = p[e]; bi = e; }
            }
            sel |= 1u << bi; ids[j] = bi; w[j] = best; s += best;
        }
        float inv = 1.0f / s;
        for (int j = 0; j < TK; ++j) {
            topk_ids[t * TK + j] = ids[j];
            topk_w[t * TK + j]   = w[j] * inv;
            atomicAdd(&counts[ids[j]], 1);
        }
    }
}

__global__ void scan_kernel(const int* __restrict__ counts, int* __restrict__ offsets)
{
    if (threadIdx.x == 0 && blockIdx.x == 0) {
        int o = 0;
        for (int e = 0; e < EE; ++e) { offsets[e] = o; o += counts[e]; }
    }
}

__global__ __launch_bounds__(256) void fill_kernel(
    const int* __restrict__ topk_ids, const float* __restrict__ topk_w,
    const int* __restrict__ offsets, int* __restrict__ fills,
    int* __restrict__ slot_token, float* __restrict__ slot_weight)
{
    int i = blockIdx.x * 256 + threadIdx.x;   // 0..4095
    int t = i >> 2;
    int e = topk_ids[i];
    int pos = offsets[e] + atomicAdd(&fills[e], 1);
    slot_token[pos]  = t;
    slot_weight[pos] = topk_w[i];
}

// ---------------- NT GEMM (A[M,K] bf16, B[N,K] fp32 -> bf16 on stage) ----------------
// MODE 0: shared gate_up  (dual B from Wsg, silu*mul -> act_s bf16 [T,ISS])
// MODE 1: shared down     (Wsd, plain fp32 store -> out [T,H])
// MODE 2: expert gate_up  (gathered A rows via token list, dual B from W1[e] -> act_x)
// MODE 3: expert down     (W2[e], weighted atomicAdd into out)
template<int MODE>
__global__ __launch_bounds__(256) void gemm_nt(
    const bf16_t* __restrict__ Abase,
    const float*  __restrict__ Bbase,
    float*  __restrict__ outF,
    bf16_t* __restrict__ outB,
    const int*   __restrict__ counts,
    const int*   __restrict__ offsets,
    const int*   __restrict__ slot_token,
    const float* __restrict__ slot_weight)
{
    constexpr bool DUAL   = (MODE == 0 || MODE == 2);
    constexpr bool EXPERT = (MODE >= 2);
    constexpr int  K      = (MODE == 1) ? ISS : (MODE == 3 ? II : HH);
    constexpr int  OSTR   = (MODE == 0) ? ISS : (MODE == 2 ? II : HH);
    constexpr int  UPOFF  = (MODE == 0) ? ISS : II;   // row offset of "up" block in B

    const int tid = threadIdx.x;
    const int n0  = blockIdx.x * BN;
    const int m0  = blockIdx.y * BM;

    int cnt = TT, off_e = 0;
    const float* Bg = Bbase;
    if constexpr (EXPERT) {
        const int e = blockIdx.z;
        cnt = counts[e];
        if (m0 >= cnt) return;           // uniform per block
        off_e = offsets[e];
        Bg = Bbase + (size_t)e * ((MODE == 2) ? (size_t)2 * II * HH : (size_t)HH * II);
    }
    const float* Bgp = Bg + (size_t)n0 * K;
    const float* Bup = Bg + (size_t)(UPOFF + n0) * K;   // unused if !DUAL

    __shared__ bf16_t As [BM][BK + LPAD];
    __shared__ bf16_t Bs0[BN][BK + LPAD];
    __shared__ bf16_t Bs1[DUAL ? BN : 1][BK + LPAD];
    __shared__ int    lds_tok[EXPERT ? BM : 1];
    __shared__ float  lds_w  [EXPERT ? BM : 1];

    int rmax = BM;
    if constexpr (EXPERT) {
        rmax = cnt - m0; if (rmax > BM) rmax = BM;
        if (tid < BM) {
            bool v = tid < rmax;
            int idx = off_e + m0 + tid;   // valid iff v
            lds_tok[tid] = v ? slot_token[idx]  : 0;
            lds_w[tid]   = v ? slot_weight[idx] : 0.0f;
        }
        __syncthreads();
    }

    const int lane = tid & 63;
    const int wv = tid >> 6;
    const int wr = wv >> 1, wc = wv & 1;
    const int lr = lane & 15, lq = lane >> 4;

    f32x4 accg[2][2], accu[2][2];
#pragma unroll
    for (int i = 0; i < 2; ++i)
#pragma unroll
        for (int j = 0; j < 2; ++j) {
            accg[i][j] = (f32x4){0.f, 0.f, 0.f, 0.f};
            accu[i][j] = (f32x4){0.f, 0.f, 0.f, 0.f};
        }

    for (int k0 = 0; k0 < K; k0 += BK) {
        // ---- stage A: 64x64 bf16, 512 chunks of 8 ----
#pragma unroll
        for (int it = 0; it < 2; ++it) {
            int chunk = it * 256 + tid;
            int r = chunk >> 3, c8 = (chunk & 7) * 8;
            bf16x8 v;
            if constexpr (MODE == 2) {
                if (r < rmax) {
                    int arow = lds_tok[r];
                    v = *(const bf16x8*)(Abase + (size_t)arow * K + k0 + c8);
                } else {
#pragma unroll
                    for (int q = 0; q < 8; ++q) v[q] = (bf16_t)0.0f;
                }
            } else {
                int arow = (MODE == 3) ? (off_e + m0 + r) : (m0 + r);
                v = *(const bf16x8*)(Abase + (size_t)arow * K + k0 + c8);
            }
            *(bf16x8*)&As[r][c8] = v;
        }
        // ---- stage B (fp32 -> bf16): 1024 float4 chunks per B tile ----
#pragma unroll
        for (int it = 0; it < 4; ++it) {
            int chunk = it * 256 + tid;
            int r = chunk >> 4, c4 = (chunk & 15) * 4;
            float4 v = *(const float4*)(Bgp + (size_t)r * K + k0 + c4);
            bf16x4 o;
            o[0] = (bf16_t)v.x; o[1] = (bf16_t)v.y; o[2] = (bf16_t)v.z; o[3] = (bf16_t)v.w;
            *(bf16x4*)&Bs0[r][c4] = o;
            if constexpr (DUAL) {
                float4 u = *(const float4*)(Bup + (size_t)r * K + k0 + c4);
                bf16x4 o2;
                o2[0] = (bf16_t)u.x; o2[1] = (bf16_t)u.y; o2[2] = (bf16_t)u.z; o2[3] = (bf16_t)u.w;
                *(bf16x4*)&Bs1[r][c4] = o2;
            }
        }
        __syncthreads();
        // ---- compute: 2 k-steps of 32 ----
#pragma unroll
        for (int kk = 0; kk < 2; ++kk) {
            bf16x8 a0 = *(const bf16x8*)&As[wr * 32 + lr]     [kk * 32 + lq * 8];
            bf16x8 a1 = *(const bf16x8*)&As[wr * 32 + 16 + lr][kk * 32 + lq * 8];
            bf16x8 b0 = *(const bf16x8*)&Bs0[wc * 32 + lr]     [kk * 32 + lq * 8];
            bf16x8 b1 = *(const bf16x8*)&Bs0[wc * 32 + 16 + lr][kk * 32 + lq * 8];
            accg[0][0] = MFMA16(a0, b0, accg[0][0]);
            accg[0][1] = MFMA16(a0, b1, accg[0][1]);
            accg[1][0] = MFMA16(a1, b0, accg[1][0]);
            accg[1][1] = MFMA16(a1, b1, accg[1][1]);
            if constexpr (DUAL) {
                bf16x8 c0 = *(const bf16x8*)&Bs1[wc * 32 + lr]     [kk * 32 + lq * 8];
                bf16x8 c1 = *(const bf16x8*)&Bs1[wc * 32 + 16 + lr][kk * 32 + lq * 8];
                accu[0][0] = MFMA16(a0, c0, accu[0][0]);
                accu[0][1] = MFMA16(a0, c1, accu[0][1]);
                accu[1][0] = MFMA16(a1, c0, accu[1][0]);
                accu[1][1] = MFMA16(a1, c1, accu[1][1]);
            }
        }
        __syncthreads();
    }

    // ---- epilogue ----  D[row = 4*lq + t][col = lr]  (m89-verified mapping)
#pragma unroll
    for (int i = 0; i < 2; ++i)
#pragma unroll
        for (int j = 0; j < 2; ++j)
#pragma unroll
            for (int t = 0; t < 4; ++t) {
                int rb = wr * 32 + i * 16 + lq * 4 + t;
                int cb = wc * 32 + j * 16 + lr;
                float g = accg[i][j][t];
                if constexpr (MODE == 0) {
                    float u = accu[i][j][t];
                    float a = g / (1.0f + expf(-g)) * u;
                    outB[(size_t)(m0 + rb) * OSTR + n0 + cb] = (bf16_t)a;
                } else if constexpr (MODE == 2) {
                    if (rb < rmax) {
                        float u = accu[i][j][t];
                        float a = g / (1.0f + expf(-g)) * u;
                        outB[(size_t)(off_e + m0 + rb) * OSTR + n0 + cb] = (bf16_t)a;
                    }
                } else if constexpr (MODE == 1) {
                    outF[(size_t)(m0 + rb) * HH + n0 + cb] = g;
                } else {  // MODE 3
                    if (rb < rmax) {
                        atomicAdd(&outF[(size_t)lds_tok[rb] * HH + n0 + cb], lds_w[rb] * g);
                    }
                }
            }
}

// ---------------- launch ----------------

extern "C" void kernel_launch(void* const* d_in, const int* in_sizes, int n_in,
                              void* d_out, int out_size, void* d_ws, size_t ws_size,
                              hipStream_t stream)
{
    const float* x   = (const float*)d_in[0];
    const float* Wg  = (const float*)d_in[1];
    const float* W1  = (const float*)d_in[2];
    const float* W2  = (const float*)d_in[3];
    const float* Wsg = (const float*)d_in[4];
    const float* Wsd = (const float*)d_in[5];
    float* out = (float*)d_out;

    char* p = (char*)d_ws;
    auto carve = [&](size_t bytes) -> char* {
        char* q = p;
        p += (bytes + 255) & ~(size_t)255;
        return q;
    };
    bf16_t* xb    = (bf16_t*)carve((size_t)TT * HH * 2);
    bf16_t* act_s = (bf16_t*)carve((size_t)TT * ISS * 2);
    bf16_t* act_x = (bf16_t*)carve((size_t)(TT * TK + BM) * II * 2);  // +BM rows slack
    int*    tids  = (int*)  carve((size_t)TT * TK * 4);
    float*  tw    = (float*)carve((size_t)TT * TK * 4);
    int*    counts= (int*)  carve(256);
    int*    offs  = (int*)  carve(256);
    int*    fills = (int*)  carve(256);
    int*    s_tok = (int*)  carve((size_t)TT * TK * 4);
    float*  s_w   = (float*)carve((size_t)TT * TK * 4);

    convert_x_kernel<<<(TT * HH / 4 + 255) / 256, 256, 0, stream>>>(
        (const float4*)x, xb, TT * HH / 4, counts, fills);
    router_kernel<<<TT, 64, 0, stream>>>(x, Wg, tids, tw, counts);
    scan_kernel<<<1, 64, 0, stream>>>(counts, offs);
    fill_kernel<<<(TT * TK) / 256, 256, 0, stream>>>(tids, tw, offs, fills, s_tok, s_w);

    // shared MLP: gate_up -> act_s, then down -> out (plain stores cover all of out)
    gemm_nt<0><<<dim3(ISS / BN, TT / BM, 1), 256, 0, stream>>>(
        xb, Wsg, nullptr, act_s, nullptr, nullptr, nullptr, nullptr);
    gemm_nt<1><<<dim3(HH / BN, TT / BM, 1), 256, 0, stream>>>(
        act_s, Wsd, out, nullptr, nullptr, nullptr, nullptr, nullptr);
    // expert MLPs: grouped gate_up -> act_x, then down with weighted atomicAdd into out
    gemm_nt<2><<<dim3(II / BN, TT / BM, EE), 256, 0, stream>>>(
        xb, W1, nullptr, act_x, counts, offs, s_tok, s_w);
    gemm_nt<3><<<dim3(HH / BN, TT / BM, EE), 256, 0, stream>>>(
        act_x, W2, out, nullptr, counts, offs, s_tok, s_w);
}